// Round 2
// baseline (769.728 us; speedup 1.0000x reference)
//
#include <hip/hip_runtime.h>
#include <hip/hip_bf16.h>
#include <stdint.h>

#define B_  32
#define L_  512
#define D_  256
#define K_  65
#define KK  4225       // K_*K_
#define NP  4352       // padded N (34 * 128)
#define M_  16384      // B_*L_

typedef __attribute__((ext_vector_type(8))) short bf16x8;
typedef __attribute__((ext_vector_type(4))) float f32x4;

typedef unsigned int u32g __attribute__((address_space(1)));
typedef unsigned int u32l __attribute__((address_space(3)));

__device__ __forceinline__ void async_ld16(const void* g, void* l) {
  __builtin_amdgcn_global_load_lds((const u32g*)g, (u32l*)l, 16, 0, 0);
}

// ---------------- prep: W' = Wt + Ws (bf16), bias' = bt + bs ----------------
__global__ __launch_bounds__(256) void pack_w_kernel(
    const float* __restrict__ Ws, const float* __restrict__ Wt,
    const float* __restrict__ bs, const float* __restrict__ bt,
    __hip_bfloat16* __restrict__ wbf, float* __restrict__ bias) {
  int p = blockIdx.x;   // 0..NP-1
  int d = threadIdx.x;  // 0..255
  float v = 0.f;
  if (p < KK) {
    int j = p % K_;
    v = Wt[(size_t)p * D_ + d] + Ws[(size_t)j * D_ + d];
    if (d == 0) bias[p] = bt[p] + bs[j];
  } else {
    if (d == 0) bias[p] = 0.f;
  }
  wbf[(size_t)p * D_ + d] = __float2bfloat16(v);
}

// ---------------- prep: x -> bf16 ----------------
__global__ __launch_bounds__(256) void pack_x_kernel(
    const float* __restrict__ x, __hip_bfloat16* __restrict__ xbf) {
  int idx = blockIdx.x * 256 + threadIdx.x;  // float4 index, total M_*D_/4
  float4 v = ((const float4*)x)[idx];
  __hip_bfloat16 o[4] = {__float2bfloat16(v.x), __float2bfloat16(v.y),
                         __float2bfloat16(v.z), __float2bfloat16(v.w)};
  *(uint2*)(xbf + (size_t)idx * 4) = *(const uint2*)o;
}

// ---------------- GEMM: F = exp((A*B^T + bias) * mask) in bf16 ----------------
// A = xbf [M_][256], B = wbf [NP][256], F [M_][NP]
__global__ __launch_bounds__(256) void gemm_exp_kernel(
    const __hip_bfloat16* __restrict__ A, const __hip_bfloat16* __restrict__ Bm,
    const float* __restrict__ bias, const float* __restrict__ mask,
    __hip_bfloat16* __restrict__ F) {
  __shared__ __align__(16) __hip_bfloat16 As[128 * 64];
  __shared__ __align__(16) __hip_bfloat16 Bs[128 * 64];
  int tid = threadIdx.x;
  int mBase = blockIdx.x * 128;
  int nBase = blockIdx.y * 128;
  int wid = tid >> 6, lane = tid & 63;
  int wm = (wid >> 1) * 64, wn = (wid & 1) * 64;
  int lrow = lane & 15, lk = (lane >> 4) * 8;

  f32x4 acc[4][4];
#pragma unroll
  for (int a = 0; a < 4; ++a)
#pragma unroll
    for (int c = 0; c < 4; ++c) acc[a][c] = (f32x4){0.f, 0.f, 0.f, 0.f};

  const __hip_bfloat16* aSrc = A + (size_t)(mBase + (tid >> 3)) * D_ + (tid & 7) * 8;
  const __hip_bfloat16* bSrc = Bm + (size_t)(nBase + (tid >> 3)) * D_ + (tid & 7) * 8;
  char* aDst = (char*)As + tid * 16;
  char* bDst = (char*)Bs + tid * 16;

  for (int kt = 0; kt < D_; kt += 64) {
#pragma unroll
    for (int i = 0; i < 4; ++i) {
      async_ld16(aSrc + (size_t)i * 32 * D_ + kt, aDst + i * 4096);
      async_ld16(bSrc + (size_t)i * 32 * D_ + kt, bDst + i * 4096);
    }
    __syncthreads();
#pragma unroll
    for (int kk = 0; kk < 64; kk += 32) {
      bf16x8 af[4], bfr[4];
#pragma unroll
      for (int f = 0; f < 4; ++f) {
        af[f]  = *(const bf16x8*)(As + (wm + f * 16 + lrow) * 64 + kk + lk);
        bfr[f] = *(const bf16x8*)(Bs + (wn + f * 16 + lrow) * 64 + kk + lk);
      }
#pragma unroll
      for (int fm = 0; fm < 4; ++fm)
#pragma unroll
        for (int fn = 0; fn < 4; ++fn)
          acc[fm][fn] = __builtin_amdgcn_mfma_f32_16x16x32_bf16(
              af[fm], bfr[fn], acc[fm][fn], 0, 0, 0);
    }
    __syncthreads();
  }

  // epilogue: E = acc + bias[col]; F = exp(E * mask[row]) stored bf16
#pragma unroll
  for (int fm = 0; fm < 4; ++fm) {
    int rbase = mBase + wm + fm * 16 + (lane >> 4) * 4;
#pragma unroll
    for (int fn = 0; fn < 4; ++fn) {
      int c = nBase + wn + fn * 16 + lrow;
      float bv = bias[c];
#pragma unroll
      for (int r = 0; r < 4; ++r) {
        int rr = rbase + r;
        float e = (acc[fm][fn][r] + bv) * mask[rr];
        float fe = exp2f(e * 1.44269504088896f);
        F[(size_t)rr * NP + c] = __float2bfloat16(fe);
      }
    }
  }
}

// ---------------- target path score: one wave per (b,t) ----------------
__global__ __launch_bounds__(256) void tgt_kernel(
    const float* __restrict__ x, const float* __restrict__ Ws,
    const float* __restrict__ bs, const float* __restrict__ Wt,
    const float* __restrict__ bt, const int* __restrict__ target,
    const float* __restrict__ mask, float* __restrict__ tgtE) {
  int gw = (blockIdx.x * 256 + threadIdx.x) >> 6;  // wave id = b*L_+t
  int lane = threadIdx.x & 63;
  int b = gw >> 9, t = gw & 511;
  int y = target[b * L_ + t];
  int prev = (t == 0) ? (K_ - 1) : target[b * L_ + t - 1];
  int p = prev * K_ + y;
  const float4* xv = (const float4*)(x + ((size_t)b * L_ + t) * D_);
  const float4* wt = (const float4*)(Wt + (size_t)p * D_);
  const float4* wv = (const float4*)(Ws + (size_t)y * D_);
  float4 xx = xv[lane], aa = wt[lane], cc = wv[lane];
  float acc = xx.x * (aa.x + cc.x) + xx.y * (aa.y + cc.y) +
              xx.z * (aa.z + cc.z) + xx.w * (aa.w + cc.w);
#pragma unroll
  for (int o = 32; o; o >>= 1) acc += __shfl_xor(acc, o);
  if (lane == 0) tgtE[gw] = (acc + bt[p] + bs[y]) * mask[b * L_ + t];
}

// ---------------- sequential forward scan (1 block per batch) ----------------
__device__ __forceinline__ void cvt_write_row(float* dstRow, int idx, uint4 u) {
  float4 f0, f1;
  f0.x = __uint_as_float(u.x << 16);  f0.y = __uint_as_float(u.x & 0xFFFF0000u);
  f0.z = __uint_as_float(u.y << 16);  f0.w = __uint_as_float(u.y & 0xFFFF0000u);
  f1.x = __uint_as_float(u.z << 16);  f1.y = __uint_as_float(u.z & 0xFFFF0000u);
  f1.z = __uint_as_float(u.w << 16);  f1.w = __uint_as_float(u.w & 0xFFFF0000u);
  ((float4*)dstRow)[idx * 2] = f0;
  ((float4*)dstRow)[idx * 2 + 1] = f1;
}

__global__ __launch_bounds__(320) void crf_fwd_kernel(
    const __hip_bfloat16* __restrict__ F, const float* __restrict__ mask,
    const float* __restrict__ tgtE, float* __restrict__ out) {
  __shared__ __align__(16) float Fb[2][4420];  // 4225 + pad(i up to 67) zeros
  __shared__ float pb[2][68];
  __shared__ float smask[512];
  __shared__ int sKi;
  __shared__ float sC;

  int b = blockIdx.x;
  int tid = threadIdx.x;
  int j = tid >> 2, s = tid & 3;
  bool act = (j < K_);
  bool leader = act && (s == 0);

  if (tid < 68) { Fb[0][4352 + tid] = 0.f; Fb[1][4352 + tid] = 0.f; }
  if (tid < 3)  { pb[0][65 + tid] = 0.f; pb[1][65 + tid] = 0.f; }
  if (tid == 0) { sC = 0.f; sKi = 0; }
  for (int i = tid; i < 512; i += 320) smask[i] = mask[b * L_ + i];

  const uint4* Fg = (const uint4*)F + (size_t)b * L_ * (NP / 8);  // 544 uint4/row

  // stage row 0
  uint4 v0[2];
#pragma unroll
  for (int r = 0; r < 2; ++r) {
    int idx = r * 320 + tid;
    if (idx < 544) v0[r] = Fg[idx];
  }
#pragma unroll
  for (int r = 0; r < 2; ++r) {
    int idx = r * 320 + tid;
    if (idx < 544) cvt_write_row(Fb[0], idx, v0[r]);
  }
  // prefetch row 1
  uint4 vp[2];
#pragma unroll
  for (int r = 0; r < 2; ++r) {
    int idx = r * 320 + tid;
    if (idx < 544) vp[r] = Fg[544 + idx];
  }
  __syncthreads();
  if (leader) pb[0][j] = Fb[0][64 * 65 + j];  // part0 = energy row i = K-1
  __syncthreads();
  if (tid < 64) {
    float vm = pb[0][tid];
    if (tid == 0) vm = fmaxf(vm, pb[0][64]);
#pragma unroll
    for (int o = 32; o; o >>= 1) vm = fmaxf(vm, __shfl_xor(vm, o));
    if (tid == 0) { int e; frexpf(vm, &e); sKi = e; }
  }
#pragma unroll
  for (int r = 0; r < 2; ++r) {
    int idx = r * 320 + tid;
    if (idx < 544) cvt_write_row(Fb[1], idx, vp[r]);
  }
  __syncthreads();

  for (int t = 1; t < L_; ++t) {
    int fcur = t & 1;
    int pcur = (t + 1) & 1;
    int ki = sKi;                       // scale applied this step (from prev iter)
    float inv = exp2f((float)(-ki));
    bool doPf = (t + 1 < L_);
    if (doPf) {
#pragma unroll
      for (int r = 0; r < 2; ++r) {
        int idx = r * 320 + tid;
        if (idx < 544) vp[r] = Fg[(size_t)(t + 1) * 544 + idx];
      }
    }
    float mval = smask[t];
    float q = 0.f;
    if (act) {
      const float* Fr = Fb[fcur];
      const float* pp = pb[pcur];
      float a0 = 0.f;
#pragma unroll
      for (int ii = 0; ii < 17; ++ii) {
        int i = s + 4 * ii;
        a0 += Fr[i * 65 + j] * pp[i];
      }
      a0 += __shfl_xor(a0, 1);
      a0 += __shfl_xor(a0, 2);
      q = a0;
    }
    if (leader) {
      float pn;
      if (mval == 1.0f) pn = q;
      else if (mval == 0.0f) pn = pb[pcur][j];
      else {
        float pold = pb[pcur][j];
        float lq = log2f(fmaxf(q, 1e-38f));
        float lo = log2f(fmaxf(pold, 1e-38f));
        pn = exp2f(lo + (lq - lo) * mval);
      }
      pb[pcur ^ 1][j] = pn * inv;
    }
    __syncthreads();
    if (tid == 0) sC += (float)ki * 0.69314718055994531f;
    if (tid < 64) {
      float vm = pb[pcur ^ 1][tid];
      if (tid == 0) vm = fmaxf(vm, pb[pcur ^ 1][64]);
#pragma unroll
      for (int o = 32; o; o >>= 1) vm = fmaxf(vm, __shfl_xor(vm, o));
      if (tid == 0) { int e; frexpf(vm, &e); sKi = e; }
    }
    if (doPf) {
#pragma unroll
      for (int r = 0; r < 2; ++r) {
        int idx = r * 320 + tid;
        if (idx < 544) cvt_write_row(Fb[fcur ^ 1], idx, vp[r]);
      }
    }
    __syncthreads();
  }

  // epilogue: loss = C + log(sum p) - sum tgtE
  if (tid < 64) {
    float ps = pb[1][tid] + ((tid == 0) ? pb[1][64] : 0.f);
#pragma unroll
    for (int o = 32; o; o >>= 1) ps += __shfl_xor(ps, o);
    float tg = 0.f;
#pragma unroll
    for (int r = 0; r < 8; ++r) tg += tgtE[b * L_ + tid + r * 64];
#pragma unroll
    for (int o = 32; o; o >>= 1) tg += __shfl_xor(tg, o);
    if (tid == 0) out[b] = sC + logf(ps) - tg;
  }
}

// ---------------- launch ----------------
extern "C" void kernel_launch(void* const* d_in, const int* in_sizes, int n_in,
                              void* d_out, int out_size, void* d_ws, size_t ws_size,
                              hipStream_t stream) {
  const float* x      = (const float*)d_in[0];
  const float* Ws     = (const float*)d_in[1];
  const float* bs     = (const float*)d_in[2];
  const float* Wt     = (const float*)d_in[3];
  const float* bt     = (const float*)d_in[4];
  const int*   target = (const int*)d_in[5];
  const float* mask   = (const float*)d_in[6];
  float* out = (float*)d_out;

  char* ws = (char*)d_ws;
  __hip_bfloat16* xbf  = (__hip_bfloat16*)(ws);               // 16384*256*2 = 8,388,608
  __hip_bfloat16* wbf  = (__hip_bfloat16*)(ws + 8388608);     // 4352*256*2  = 2,228,224
  float*          bias = (float*)(ws + 10616832);             // 4352*4      = 17,408
  __hip_bfloat16* F    = (__hip_bfloat16*)(ws + 10634240);    // 16384*4352*2 = 142,606,336
  float*          tgtE = (float*)(ws + 153240576);            // 16384*4     = 65,536
  // total 153,306,112 bytes

  hipLaunchKernelGGL(pack_w_kernel, dim3(NP), dim3(256), 0, stream,
                     Ws, Wt, bs, bt, wbf, bias);
  hipLaunchKernelGGL(pack_x_kernel, dim3(M_ * D_ / 4 / 256), dim3(256), 0, stream,
                     x, xbf);
  hipLaunchKernelGGL(gemm_exp_kernel, dim3(M_ / 128, NP / 128), dim3(256), 0, stream,
                     xbf, wbf, bias, mask, F);
  hipLaunchKernelGGL(tgt_kernel, dim3(M_ / 4), dim3(256), 0, stream,
                     x, Ws, bs, Wt, bt, target, mask, tgtE);
  hipLaunchKernelGGL(crf_fwd_kernel, dim3(B_), dim3(320), 0, stream,
                     F, mask, tgtE, out);
}

// Round 3
// 191.946 us; speedup vs baseline: 4.0101x; 4.0101x over previous
//
#include <hip/hip_runtime.h>
#include <hip/hip_bf16.h>
#include <stdint.h>

#define B_  32
#define L_  512
#define D_  256
#define K_  65
#define KK  4225       // K_*K_
#define NP  4352       // padded N (34 * 128)
#define M_  16384      // B_*L_
#define MSTR 4352      // per-matrix element stride (65x65 compact rows + pad)
#define LSTR 104       // LDS row stride (96 + 8 pad -> 2-way banks only)
#define LMAT 9984      // 96*104

typedef __attribute__((ext_vector_type(8))) short bf16x8;
typedef __attribute__((ext_vector_type(4))) float f32x4;

typedef unsigned int u32g __attribute__((address_space(1)));
typedef unsigned int u32l __attribute__((address_space(3)));

__device__ __forceinline__ void async_ld16(const void* g, void* l) {
  __builtin_amdgcn_global_load_lds((const u32g*)g, (u32l*)l, 16, 0, 0);
}

// ---------------- prep: W' = Wt + Ws (bf16), bias' = bt + bs ----------------
__global__ __launch_bounds__(256) void pack_w_kernel(
    const float* __restrict__ Ws, const float* __restrict__ Wt,
    const float* __restrict__ bs, const float* __restrict__ bt,
    __hip_bfloat16* __restrict__ wbf, float* __restrict__ bias) {
  int p = blockIdx.x;   // 0..NP-1
  int d = threadIdx.x;  // 0..255
  float v = 0.f;
  if (p < KK) {
    int j = p % K_;
    v = Wt[(size_t)p * D_ + d] + Ws[(size_t)j * D_ + d];
    if (d == 0) bias[p] = bt[p] + bs[j];
  } else {
    if (d == 0) bias[p] = 0.f;
  }
  wbf[(size_t)p * D_ + d] = __float2bfloat16(v);
}

// ---------------- prep: x -> bf16 ----------------
__global__ __launch_bounds__(256) void pack_x_kernel(
    const float* __restrict__ x, __hip_bfloat16* __restrict__ xbf) {
  int idx = blockIdx.x * 256 + threadIdx.x;  // float4 index, total M_*D_/4
  float4 v = ((const float4*)x)[idx];
  __hip_bfloat16 o[4] = {__float2bfloat16(v.x), __float2bfloat16(v.y),
                         __float2bfloat16(v.z), __float2bfloat16(v.w)};
  *(uint2*)(xbf + (size_t)idx * 4) = *(const uint2*)o;
}

// ---------------- GEMM: F = exp((A*B^T + bias) * mask) in bf16 ----------------
__global__ __launch_bounds__(256) void gemm_exp_kernel(
    const __hip_bfloat16* __restrict__ A, const __hip_bfloat16* __restrict__ Bm,
    const float* __restrict__ bias, const float* __restrict__ mask,
    __hip_bfloat16* __restrict__ F) {
  __shared__ __align__(16) __hip_bfloat16 As[128 * 64];
  __shared__ __align__(16) __hip_bfloat16 Bs[128 * 64];
  int tid = threadIdx.x;
  int mBase = blockIdx.x * 128;
  int nBase = blockIdx.y * 128;
  int wid = tid >> 6, lane = tid & 63;
  int wm = (wid >> 1) * 64, wn = (wid & 1) * 64;
  int lrow = lane & 15, lk = (lane >> 4) * 8;

  f32x4 acc[4][4];
#pragma unroll
  for (int a = 0; a < 4; ++a)
#pragma unroll
    for (int c = 0; c < 4; ++c) acc[a][c] = (f32x4){0.f, 0.f, 0.f, 0.f};

  const __hip_bfloat16* aSrc = A + (size_t)(mBase + (tid >> 3)) * D_ + (tid & 7) * 8;
  const __hip_bfloat16* bSrc = Bm + (size_t)(nBase + (tid >> 3)) * D_ + (tid & 7) * 8;
  char* aDst = (char*)As + tid * 16;
  char* bDst = (char*)Bs + tid * 16;

  for (int kt = 0; kt < D_; kt += 64) {
#pragma unroll
    for (int i = 0; i < 4; ++i) {
      async_ld16(aSrc + (size_t)i * 32 * D_ + kt, aDst + i * 4096);
      async_ld16(bSrc + (size_t)i * 32 * D_ + kt, bDst + i * 4096);
    }
    __syncthreads();
#pragma unroll
    for (int kk = 0; kk < 64; kk += 32) {
      bf16x8 af[4], bfr[4];
#pragma unroll
      for (int f = 0; f < 4; ++f) {
        af[f]  = *(const bf16x8*)(As + (wm + f * 16 + lrow) * 64 + kk + lk);
        bfr[f] = *(const bf16x8*)(Bs + (wn + f * 16 + lrow) * 64 + kk + lk);
      }
#pragma unroll
      for (int fm = 0; fm < 4; ++fm)
#pragma unroll
        for (int fn = 0; fn < 4; ++fn)
          acc[fm][fn] = __builtin_amdgcn_mfma_f32_16x16x32_bf16(
              af[fm], bfr[fn], acc[fm][fn], 0, 0, 0);
    }
    __syncthreads();
  }

#pragma unroll
  for (int fm = 0; fm < 4; ++fm) {
    int rbase = mBase + wm + fm * 16 + (lane >> 4) * 4;
#pragma unroll
    for (int fn = 0; fn < 4; ++fn) {
      int c = nBase + wn + fn * 16 + lrow;
      float bv = bias[c];
#pragma unroll
      for (int r = 0; r < 4; ++r) {
        int rr = rbase + r;
        float mval = mask[rr];
        float e = acc[fm][fn][r] + bv;
        float fe;
        if (mval != 0.0f) {
          fe = exp2f(e * mval * 1.4426950408889634f);
        } else if ((rr & 511) != 0) {
          // masked step t>0: transition must be identity (part unchanged)
          int ii = c / 65, jj = c - ii * 65;
          fe = (ii == jj) ? 1.0f : 0.0f;
        } else {
          fe = 1.0f;  // t==0 masked: exp(0)
        }
        F[(size_t)rr * NP + c] = __float2bfloat16(fe);
      }
    }
  }
}

// ---------------- target path score: one wave per (b,t) ----------------
__global__ __launch_bounds__(256) void tgt_kernel(
    const float* __restrict__ x, const float* __restrict__ Ws,
    const float* __restrict__ bs, const float* __restrict__ Wt,
    const float* __restrict__ bt, const int* __restrict__ target,
    const float* __restrict__ mask, float* __restrict__ tgtE) {
  int gw = (blockIdx.x * 256 + threadIdx.x) >> 6;  // wave id = b*L_+t
  int lane = threadIdx.x & 63;
  int b = gw >> 9, t = gw & 511;
  int y = target[b * L_ + t];
  int prev = (t == 0) ? (K_ - 1) : target[b * L_ + t - 1];
  int p = prev * K_ + y;
  const float4* xv = (const float4*)(x + ((size_t)b * L_ + t) * D_);
  const float4* wt = (const float4*)(Wt + (size_t)p * D_);
  const float4* wv = (const float4*)(Ws + (size_t)y * D_);
  float4 xx = xv[lane], aa = wt[lane], cc = wv[lane];
  float acc = xx.x * (aa.x + cc.x) + xx.y * (aa.y + cc.y) +
              xx.z * (aa.z + cc.z) + xx.w * (aa.w + cc.w);
#pragma unroll
  for (int o = 32; o; o >>= 1) acc += __shfl_xor(acc, o);
  if (lane == 0) tgtE[gw] = (acc + bt[p] + bs[y]) * mask[b * L_ + t];
}

// ---------------- matrix-chain product kernels ----------------
// MODE 0 (T1): src = F (matrix t at F + (b*512+t)*MSTR, row-major [i][j]).
//   Block (c,b): product F_{t0} ... F_{t0+nb}, chunk c covers t in
//   [32c..32c+31] (chunk 0 starts at t=1). B-operand staged TRANSPOSED.
// MODE 1 (T2): src = chunkOut. Block (m,b): product of chunk mats 4m..4m+3.
//   Inputs 4m+1..3 are stored transposed by T1 -> B staged by DIRECT copy.
// mfma primitive: C[r][n] = sum_k Als[r][k] * Bls[n][k]  (both row-major LDS)
template <int MODE>
__global__ __launch_bounds__(256, 2) void chain_kernel(
    const __hip_bfloat16* __restrict__ src,
    const int* __restrict__ scIn,
    __hip_bfloat16* __restrict__ outM,
    int* __restrict__ scOut) {
  __shared__ __align__(16) __hip_bfloat16 lds[3 * LMAT];  // A | G0 | G1
  __shared__ float red[4];
  __hip_bfloat16* Als = lds;
  ushort* A16 = (ushort*)Als;

  int tid = threadIdx.x, wid = tid >> 6, lane = tid & 63;
  int wr = wid >> 1, wc = wid & 1;
  int b = blockIdx.y, cx = blockIdx.x;

  long mat0; int nb, outIdx, Kacc; bool trOut;
  if (MODE == 0) {
    mat0 = (long)b * 512 + (cx == 0 ? 1 : 32 * cx);
    nb = (cx == 0) ? 30 : 31;
    outIdx = b * 16 + cx;
    trOut = (cx & 3) != 0;
    Kacc = 0;
  } else {
    int i0 = b * 16 + 4 * cx;
    mat0 = i0;
    nb = 3;
    outIdx = b * 4 + cx;
    trOut = true;
    Kacc = scIn[i0] + scIn[i0 + 1] + scIn[i0 + 2] + scIn[i0 + 3];
  }

  // zero all 3 LDS buffers (pads must be 0)
  for (int z = tid; z < 3 * LMAT / 2; z += 256) ((uint*)lds)[z] = 0u;

  // precompute B-staging LDS element offsets (packed lo|hi<<16)
  int nfull = (tid < 64) ? 9 : 8;
  uint bofs[9];
#pragma unroll
  for (int m = 0; m < 9; ++m) {
    uint pk = 0;
    if (m < nfull) {
      int e2 = 2 * (tid + 256 * m);
      int a0 = e2 / 65, b0 = e2 - a0 * 65;
      int a1 = (b0 < 64) ? a0 : a0 + 1, b1 = (b0 < 64) ? b0 + 1 : 0;
      int o0, o1;
      if (MODE == 0) { o0 = b0 * LSTR + a0; o1 = b1 * LSTR + a1; }  // transpose
      else           { o0 = a0 * LSTR + b0; o1 = a1 * LSTR + b1; }  // copy
      pk = (uint)o0 | ((uint)o1 << 16);
    }
    bofs[m] = pk;
  }
  __syncthreads();  // zero-fill visible before scatter writes

  // A-init: direct row-major copy of matrix mat0
  {
    const __hip_bfloat16* sA = src + (size_t)mat0 * MSTR;
    const uint* s32 = (const uint*)sA;
#pragma unroll
    for (int m = 0; m < 9; ++m) {
      if (m < nfull) {
        int e = tid + 256 * m;
        uint v = s32[e];
        int e2 = 2 * e;
        int a0 = e2 / 65, b0 = e2 - a0 * 65;
        int a1 = (b0 < 64) ? a0 : a0 + 1, b1 = (b0 < 64) ? b0 + 1 : 0;
        A16[a0 * LSTR + b0] = (ushort)(v & 0xFFFFu);
        A16[a1 * LSTR + b1] = (ushort)(v >> 16);
      }
    }
    if (tid == 0) A16[64 * LSTR + 64] = ((const ushort*)sA)[4224];
  }
  // stage B_0 into G buffer 0
  {
    const uint* s32 = (const uint*)(src + (size_t)(mat0 + 1) * MSTR);
    ushort* G = (ushort*)(lds + LMAT);
#pragma unroll
    for (int m = 0; m < 9; ++m) {
      if (m < nfull) {
        uint v = s32[tid + 256 * m];
        uint pk = bofs[m];
        G[pk & 0xFFFFu] = (ushort)(v & 0xFFFFu);
        G[pk >> 16] = (ushort)(v >> 16);
      }
    }
    if (tid == 0) G[64 * LSTR + 64] = ((const ushort*)s32)[8448 / 2 * 0 + 4224];
  }
  __syncthreads();

  for (int s = 0; s < nb; ++s) {
    bool pf = (s + 1 < nb);
    uint gv[9]; ushort tl = 0;
    if (pf) {
      const uint* s32 = (const uint*)(src + (size_t)(mat0 + 2 + s) * MSTR);
#pragma unroll
      for (int m = 0; m < 9; ++m)
        if (m < nfull) gv[m] = s32[tid + 256 * m];
      if (tid == 0) tl = ((const ushort*)s32)[4224];
    }

    // matmul: C = A * G  (G holds B^T layout [n][k])
    f32x4 acc[3][3];
#pragma unroll
    for (int r = 0; r < 3; ++r)
#pragma unroll
      for (int c = 0; c < 3; ++c) acc[r][c] = (f32x4){0.f, 0.f, 0.f, 0.f};
    const __hip_bfloat16* Gc = lds + (1 + (s & 1)) * LMAT;
#pragma unroll
    for (int kk = 0; kk < 96; kk += 32) {
      bf16x8 af[3], bg[3];
#pragma unroll
      for (int r = 0; r < 3; ++r)
        af[r] = *(const bf16x8*)(Als + ((3 * wr + r) * 16 + (lane & 15)) * LSTR + kk + (lane >> 4) * 8);
#pragma unroll
      for (int c = 0; c < 3; ++c)
        bg[c] = *(const bf16x8*)(Gc + ((3 * wc + c) * 16 + (lane & 15)) * LSTR + kk + (lane >> 4) * 8);
#pragma unroll
      for (int r = 0; r < 3; ++r)
#pragma unroll
        for (int c = 0; c < 3; ++c)
          acc[r][c] = __builtin_amdgcn_mfma_f32_16x16x32_bf16(af[r], bg[c], acc[r][c], 0, 0, 0);
    }
    __syncthreads();  // all waves done reading Als

    // block max -> power-of-2 renorm
    float mx = 0.f;
#pragma unroll
    for (int r = 0; r < 3; ++r)
#pragma unroll
      for (int c = 0; c < 3; ++c)
#pragma unroll
        for (int q = 0; q < 4; ++q) mx = fmaxf(mx, acc[r][c][q]);
#pragma unroll
    for (int o = 32; o; o >>= 1) mx = fmaxf(mx, __shfl_xor(mx, o));
    if (lane == 0) red[wid] = mx;
    __syncthreads();
    mx = fmaxf(fmaxf(red[0], red[1]), fmaxf(red[2], red[3]));
    int k; frexpf(mx, &k);
    Kacc += k;
    float sc = ldexpf(1.0f, -k);
    bool last = (s == nb - 1);

    // writeback scaled bf16 into Als (or final global store)
#pragma unroll
    for (int r = 0; r < 3; ++r) {
      int R0 = (3 * wr + r) * 16 + (lane >> 4) * 4;
#pragma unroll
      for (int c = 0; c < 3; ++c) {
        int C0 = (3 * wc + c) * 16 + (lane & 15);
#pragma unroll
        for (int q = 0; q < 4; ++q) {
          __hip_bfloat16 h = __float2bfloat16(acc[r][c][q] * sc);
          if (!last) {
            Als[(R0 + q) * LSTR + C0] = h;
          } else if (R0 + q < K_ && C0 < K_) {
            size_t oo = (size_t)outIdx * MSTR +
                        (trOut ? (C0 * 65 + R0 + q) : ((R0 + q) * 65 + C0));
            outM[oo] = h;
          }
        }
      }
    }
    // stage next B
    if (pf) {
      ushort* G = (ushort*)(lds + (1 + ((s + 1) & 1)) * LMAT);
#pragma unroll
      for (int m = 0; m < 9; ++m) {
        if (m < nfull) {
          uint v = gv[m];
          uint pk = bofs[m];
          G[pk & 0xFFFFu] = (ushort)(v & 0xFFFFu);
          G[pk >> 16] = (ushort)(v >> 16);
        }
      }
      if (tid == 0) G[64 * LSTR + 64] = tl;
    }
    __syncthreads();
  }
  if (tid == 0) scOut[outIdx] = Kacc;
}

// ---------------- final: p0 through 4 matrices, logsumexp, -tgt ----------------
__global__ __launch_bounds__(256) void final_kernel(
    const __hip_bfloat16* __restrict__ F, const __hip_bfloat16* __restrict__ levA,
    const int* __restrict__ sc2, const float* __restrict__ tgtE,
    float* __restrict__ out) {
  __shared__ float v[2][80];
  __shared__ float rs[8];
  int b = blockIdx.x, tid = threadIdx.x;
  // p0[j] = F_0[64][j]
  if (tid < K_)
    v[0][tid] = __bfloat162float(F[(size_t)b * 512 * NP + 64 * 65 + tid]);
  __syncthreads();
  int cur = 0;
  for (int m = 0; m < 4; ++m) {
    const __hip_bfloat16* T = levA + (size_t)(b * 4 + m) * MSTR;  // transposed [j][i]
    if (tid < K_) {
      float s = 0.f;
      for (int i = 0; i < K_; ++i)
        s += v[cur][i] * __bfloat162float(T[tid * 65 + i]);
      v[1 - cur][tid] = s;
    }
    cur ^= 1;
    __syncthreads();
  }
  // tgt sum (512 values) per wave, then LDS
  float tv = tgtE[b * 512 + tid] + tgtE[b * 512 + 256 + tid];
#pragma unroll
  for (int o = 32; o; o >>= 1) tv += __shfl_xor(tv, o);
  if ((tid & 63) == 0) rs[4 + (tid >> 6)] = tv;
  if (tid < 64) {
    float zz = v[cur][tid] + ((tid == 0) ? v[cur][64] : 0.f);
#pragma unroll
    for (int o = 32; o; o >>= 1) zz += __shfl_xor(zz, o);
    if (tid == 0) rs[0] = zz;
  }
  __syncthreads();
  if (tid == 0) {
    float tg = rs[4] + rs[5] + rs[6] + rs[7];
    int S = sc2[4 * b] + sc2[4 * b + 1] + sc2[4 * b + 2] + sc2[4 * b + 3];
    out[b] = logf(rs[0]) + 0.6931471805599453f * (float)S - tg;
  }
}

// ---------------- launch ----------------
extern "C" void kernel_launch(void* const* d_in, const int* in_sizes, int n_in,
                              void* d_out, int out_size, void* d_ws, size_t ws_size,
                              hipStream_t stream) {
  const float* x      = (const float*)d_in[0];
  const float* Ws     = (const float*)d_in[1];
  const float* bs     = (const float*)d_in[2];
  const float* Wt     = (const float*)d_in[3];
  const float* bt     = (const float*)d_in[4];
  const int*   target = (const int*)d_in[5];
  const float* mask   = (const float*)d_in[6];
  float* out = (float*)d_out;

  char* ws = (char*)d_ws;
  __hip_bfloat16* xbf  = (__hip_bfloat16*)(ws);               // 8,388,608 B (dead after GEMM)
  __hip_bfloat16* wbf  = (__hip_bfloat16*)(ws + 8388608);     // 2,228,224 B (dead after GEMM)
  float*          bias = (float*)(ws + 10616832);             // 17,408 B
  __hip_bfloat16* F    = (__hip_bfloat16*)(ws + 10634240);    // 142,606,336 B
  float*          tgtE = (float*)(ws + 153240576);            // 65,536 B
  // region reuse (after GEMM no longer needs xbf/wbf):
  __hip_bfloat16* chunkOut = (__hip_bfloat16*)(ws);           // 512*8704 = 4,456,448 B
  __hip_bfloat16* levA     = (__hip_bfloat16*)(ws + 8388608); // 128*8704 = 1,114,112 B
  int*            sc1      = (int*)(ws + 9502720);            // 2,048 B
  int*            sc2      = (int*)(ws + 9504768);            // 512 B

  hipLaunchKernelGGL(pack_w_kernel, dim3(NP), dim3(256), 0, stream,
                     Ws, Wt, bs, bt, wbf, bias);
  hipLaunchKernelGGL(pack_x_kernel, dim3(M_ * D_ / 4 / 256), dim3(256), 0, stream,
                     x, xbf);
  hipLaunchKernelGGL(gemm_exp_kernel, dim3(M_ / 128, NP / 128), dim3(256), 0, stream,
                     xbf, wbf, bias, mask, F);
  hipLaunchKernelGGL(tgt_kernel, dim3(M_ / 4), dim3(256), 0, stream,
                     x, Ws, bs, Wt, bt, target, mask, tgtE);
  hipLaunchKernelGGL((chain_kernel<0>), dim3(16, 32), dim3(256), 0, stream,
                     F, (const int*)nullptr, chunkOut, sc1);
  hipLaunchKernelGGL((chain_kernel<1>), dim3(4, 32), dim3(256), 0, stream,
                     chunkOut, sc1, levA, sc2);
  hipLaunchKernelGGL(final_kernel, dim3(B_), dim3(256), 0, stream,
                     F, levA, sc2, tgtE, out);
}